// Round 7
// baseline (244.173 us; speedup 1.0000x reference)
//
#include <hip/hip_runtime.h>

typedef float v2f __attribute__((ext_vector_type(2)));

#define N_PTS  20000
#define Q      8                           // queries per thread (4 packed pairs)
#define QPB    (256 * Q)                   // 2048
#define NQB    ((N_PTS + QPB - 1) / QPB)   // 10
#define NSEG   64                          // ref segments -> grid 1280 = 5/CU
#define SEGLEN ((N_PTS + NSEG - 1) / NSEG) // 313
#define QB79   79                          // fallback

// Broadcast-pair ref record: {-2x,-2x}{-2y,-2y}{-2z,-2z}{sd,sd}, 32 B.
// Uniform s_load_dwordx8 -> four SGPR pairs, directly usable as VOP3P srcs.
struct RefB { v2f nx, ny, nz, w; };

// ---- numpy-exact helpers ----
__device__ __forceinline__ float np_self_dot(float x, float y, float z) {
    return __fadd_rn(__fadd_rn(__fmul_rn(x, x), __fmul_rn(y, y)),
                     __fmul_rn(z, z));
}
__device__ __forceinline__ unsigned int ordmap(float f) {
    unsigned int b = __float_as_uint(f);
    return (b & 0x80000000u) ? ~b : (b | 0x80000000u);
}

// ---- forced VOP3P packed f32 (IEEE RN per half, no fusion possible) ----
__device__ __forceinline__ v2f pk_mul_sv(v2f s, v2f v) {
    v2f d; asm("v_pk_mul_f32 %0, %1, %2" : "=v"(d) : "s"(s), "v"(v)); return d;
}
__device__ __forceinline__ v2f pk_add_sv(v2f s, v2f v) {
    v2f d; asm("v_pk_add_f32 %0, %1, %2" : "=v"(d) : "s"(s), "v"(v)); return d;
}
__device__ __forceinline__ v2f pk_add_vv(v2f a, v2f b) {
    v2f d; asm("v_pk_add_f32 %0, %1, %2" : "=v"(d) : "v"(a), "v"(b)); return d;
}

// Pack both clouds as broadcast-pair records + init atomic keys.
__global__ __launch_bounds__(256) void chamfer_prep(
    const float* __restrict__ preds, const float* __restrict__ gts,
    RefB* __restrict__ ppack, RefB* __restrict__ gpack,
    unsigned long long* __restrict__ keys)
{
    int t = blockIdx.x * 256 + threadIdx.x;
    if (t < 2 * N_PTS) {
        const float* src = (t < N_PTS) ? preds : gts;
        RefB*        dst = (t < N_PTS) ? ppack : gpack;
        int i = (t < N_PTS) ? t : t - N_PTS;
        float x = src[i*3+0], y = src[i*3+1], z = src[i*3+2];
        float nx = -(x + x), ny = -(y + y), nz = -(z + z);  // exact
        float w  = np_self_dot(x, y, z);
        RefB r;
        r.nx = (v2f){nx, nx}; r.ny = (v2f){ny, ny};
        r.nz = (v2f){nz, nz}; r.w  = (v2f){w, w};
        dst[i] = r;
        keys[t] = ~0ULL;
    }
}

// Main: per ref j (uniform scalar load), per query-pair:
//   m_i = pk_mul(ref_neg2, q_i)   (3)     zz = (m0+m1)+m2  (2)
//   s   = pk_add(ref_w, sqv)      (1)     d  = s + zz      (1)
// d.half = fl( fl(sq+sr) - fl(2*fl(zz)) )  == numpy P bit-exactly:
// negation & x2 are exact in RN, so fl(-2a-2b) = -2*fl(a+b) elementwise.
// Strict < with ascending j == numpy first-occurrence argmin; cross-segment
// merge via u64 atomicMin of (ordmap(d)<<32 | idx). Deterministic.
__global__ __launch_bounds__(256, 4) void chamfer_main(
    const float* __restrict__ preds, const float* __restrict__ gts,
    const RefB* __restrict__ ppack, const RefB* __restrict__ gpack,
    unsigned long long* __restrict__ keys)
{
    int bid = blockIdx.x;
    int dir = bid / (NQB * NSEG);
    int rem = bid - dir * (NQB * NSEG);
    int seg = rem / NQB;
    int qb  = rem - seg * NQB;

    const float* qpts = (dir == 0) ? preds : gts;
    const RefB*  rb   = (dir == 0) ? gpack : ppack;

    int qbase = qb * QPB + threadIdx.x;

    // 4 chainpairs, each holding 2 queries in packed halves (lo=A, hi=B)
#define LOADQP(c)                                                         \
    v2f qx##c, qy##c, qz##c, sq##c;                                       \
    float bestA##c, bestB##c; int idxA##c, idxB##c;                       \
    {   int qA = qbase + (2*c) * 256, qB = qbase + (2*c+1) * 256;         \
        int cA = (qA < N_PTS) ? qA : (N_PTS - 1);                         \
        int cB = (qB < N_PTS) ? qB : (N_PTS - 1);                         \
        float xA = qpts[cA*3+0], yA = qpts[cA*3+1], zA = qpts[cA*3+2];    \
        float xB = qpts[cB*3+0], yB = qpts[cB*3+1], zB = qpts[cB*3+2];    \
        qx##c = (v2f){xA, xB}; qy##c = (v2f){yA, yB};                     \
        qz##c = (v2f){zA, zB};                                            \
        sq##c = (v2f){np_self_dot(xA, yA, zA), np_self_dot(xB, yB, zB)};  \
        bestA##c = 3.4e38f; bestB##c = 3.4e38f;                           \
        idxA##c = 0; idxB##c = 0; }
    LOADQP(0) LOADQP(1) LOADQP(2) LOADQP(3)
#undef LOADQP

    int s0 = seg * SEGLEN;
    int s1 = min(s0 + SEGLEN, N_PTS);

#define CHAINP(c)                                                         \
    {   v2f m0 = pk_mul_sv(rnx, qx##c);                                   \
        v2f m1 = pk_mul_sv(rny, qy##c);                                   \
        v2f m2 = pk_mul_sv(rnz, qz##c);                                   \
        v2f zz = pk_add_vv(pk_add_vv(m0, m1), m2);                        \
        v2f s  = pk_add_sv(rww, sq##c);                                   \
        v2f d  = pk_add_vv(s, zz);                                        \
        bool la = d.x < bestA##c;                                         \
        bestA##c = la ? d.x : bestA##c;  idxA##c = la ? j : idxA##c;      \
        bool lb = d.y < bestB##c;                                         \
        bestB##c = lb ? d.y : bestB##c;  idxB##c = lb ? j : idxB##c; }

    #pragma unroll 2
    for (int j = s0; j < s1; ++j) {
        RefB r = rb[j];                  // wave-uniform -> s_load_dwordx8
        v2f rnx = r.nx, rny = r.ny, rnz = r.nz, rww = r.w;
        CHAINP(0) CHAINP(1) CHAINP(2) CHAINP(3)
    }
#undef CHAINP

#define EMIT(c)                                                           \
    {   int qA = qbase + (2*c) * 256, qB = qbase + (2*c+1) * 256;         \
        if (qA < N_PTS) {                                                 \
            unsigned long long k =                                        \
                ((unsigned long long)ordmap(bestA##c) << 32) |            \
                (unsigned int)idxA##c;                                    \
            atomicMin(&keys[dir * N_PTS + qA], k);                        \
        }                                                                 \
        if (qB < N_PTS) {                                                 \
            unsigned long long k =                                        \
                ((unsigned long long)ordmap(bestB##c) << 32) |            \
                (unsigned int)idxB##c;                                    \
            atomicMin(&keys[dir * N_PTS + qB], k);                        \
        } }
    EMIT(0) EMIT(1) EMIT(2) EMIT(3)
#undef EMIT
}

__global__ __launch_bounds__(256) void chamfer_finalize(
    const unsigned long long* __restrict__ keys,
    float* __restrict__ out)
{
    int t = blockIdx.x * 256 + threadIdx.x;
    if (t >= 2 * N_PTS) return;
    int dir = t / N_PTS;
    int q   = t - dir * N_PTS;
    unsigned long long key = keys[dir * N_PTS + q];
    unsigned int hi = (unsigned int)(key >> 32);
    unsigned int lo = (unsigned int)(key & 0xFFFFFFFFu);
    unsigned int b  = (hi & 0x80000000u) ? (hi ^ 0x80000000u) : ~hi;
    out[dir * N_PTS + q]       = __uint_as_float(b);   // dist1 | dist2
    out[(2 + dir) * N_PTS + q] = (float)lo;            // idx1  | idx2
}

// ---- fallback (tiny workspace): direct kernel, correct but slow ----
__device__ __forceinline__ float np_pair(float sq, float sr,
                                         float qx, float qy, float qz,
                                         float rx, float ry, float rz) {
    float zz = __fadd_rn(__fadd_rn(__fmul_rn(qx, rx), __fmul_rn(qy, ry)),
                         __fmul_rn(qz, rz));
    return __fsub_rn(__fadd_rn(sq, sr), __fadd_rn(zz, zz));
}

__global__ __launch_bounds__(256) void chamfer_direct_kernel(
    const float* __restrict__ preds,
    const float* __restrict__ gts,
    float* __restrict__ out)
{
    __shared__ float4 spts[256];
    int bid = blockIdx.x;
    int dir = bid / QB79;
    int qb  = bid - dir * QB79;
    int q   = qb * 256 + threadIdx.x;

    const float* qpts = (dir == 0) ? preds : gts;
    const float* rpts = (dir == 0) ? gts   : preds;

    int qc = (q < N_PTS) ? q : (N_PTS - 1);
    float qx = qpts[qc*3+0], qy = qpts[qc*3+1], qz = qpts[qc*3+2];
    float sq = np_self_dot(qx, qy, qz);
    float best = 3.4e38f;
    int   bidx = 0;

    for (int t = 0; t < N_PTS; t += 256) {
        int cnt = min(256, N_PTS - t);
        __syncthreads();
        if ((int)threadIdx.x < cnt) {
            int j = t + threadIdx.x;
            float rx = rpts[j*3+0], ry = rpts[j*3+1], rz = rpts[j*3+2];
            spts[threadIdx.x] = make_float4(rx, ry, rz, np_self_dot(rx, ry, rz));
        }
        __syncthreads();
        for (int k = 0; k < cnt; ++k) {
            float4 r = spts[k];
            float d = np_pair(sq, r.w, qx, qy, qz, r.x, r.y, r.z);
            if (d < best) { best = d; bidx = t + k; }
        }
    }
    if (q < N_PTS) {
        out[dir * N_PTS + q]       = best;
        out[(2 + dir) * N_PTS + q] = (float)bidx;
    }
}

extern "C" void kernel_launch(void* const* d_in, const int* in_sizes, int n_in,
                              void* d_out, int out_size, void* d_ws, size_t ws_size,
                              hipStream_t stream) {
    const float* preds = (const float*)d_in[0];  // [20000, 3]
    const float* gts   = (const float*)d_in[1];  // [1, 20000, 3]
    float* out = (float*)d_out;

    size_t pack_bytes = (size_t)N_PTS * sizeof(RefB);                      // 640 KB each
    size_t keys_bytes = (size_t)2 * N_PTS * sizeof(unsigned long long);    // 320 KB
    size_t need = 2 * pack_bytes + keys_bytes;                             // ~1.6 MB

    if (ws_size >= need) {
        RefB* ppack = (RefB*)d_ws;
        RefB* gpack = (RefB*)((char*)d_ws + pack_bytes);
        unsigned long long* keys =
            (unsigned long long*)((char*)d_ws + 2 * pack_bytes);

        chamfer_prep<<<(2 * N_PTS + 255) / 256, 256, 0, stream>>>(
            preds, gts, ppack, gpack, keys);
        chamfer_main<<<2 * NQB * NSEG, 256, 0, stream>>>(
            preds, gts, ppack, gpack, keys);              // 1280 blocks
        chamfer_finalize<<<(2 * N_PTS + 255) / 256, 256, 0, stream>>>(keys, out);
    } else {
        chamfer_direct_kernel<<<2 * QB79, 256, 0, stream>>>(preds, gts, out);
    }
}

// Round 8
// 242.712 us; speedup vs baseline: 1.0060x; 1.0060x over previous
//
#include <hip/hip_runtime.h>

typedef float v2f __attribute__((ext_vector_type(2)));

#define N_PTS  20000
#define Q      8                           // queries per thread (4 packed pairs)
#define QPB    (256 * Q)                   // 2048
#define NQB    ((N_PTS + QPB - 1) / QPB)   // 10
#define NSEG   64                          // ref segments -> grid 1280 = 5/CU
#define SEGLEN ((N_PTS + NSEG - 1) / NSEG) // 313
#define QB79   79                          // fallback

// Broadcast-pair ref record: {-2x,-2x}{-2y,-2y}{-2z,-2z}{sd,sd}, 32 B.
// Wave-uniform -> s_load_dwordx8 -> four SGPR pairs feeding VOP3P directly.
struct RefB { v2f nx, ny, nz, w; };

// ---- numpy-exact helpers ----
__device__ __forceinline__ float np_self_dot(float x, float y, float z) {
    return __fadd_rn(__fadd_rn(__fmul_rn(x, x), __fmul_rn(y, y)),
                     __fmul_rn(z, z));
}
__device__ __forceinline__ unsigned int ordmap(float f) {
    unsigned int b = __float_as_uint(f);
    return (b & 0x80000000u) ? ~b : (b | 0x80000000u);
}

// Pack both clouds as broadcast-pair records + init atomic keys.
__global__ __launch_bounds__(256) void chamfer_prep(
    const float* __restrict__ preds, const float* __restrict__ gts,
    RefB* __restrict__ ppack, RefB* __restrict__ gpack,
    unsigned long long* __restrict__ keys)
{
    int t = blockIdx.x * 256 + threadIdx.x;
    if (t < 2 * N_PTS) {
        const float* src = (t < N_PTS) ? preds : gts;
        RefB*        dst = (t < N_PTS) ? ppack : gpack;
        int i = (t < N_PTS) ? t : t - N_PTS;
        float x = src[i*3+0], y = src[i*3+1], z = src[i*3+2];
        float nx = -(x + x), ny = -(y + y), nz = -(z + z);  // exact in RN
        float w  = np_self_dot(x, y, z);
        RefB r;
        r.nx = (v2f){nx, nx}; r.ny = (v2f){ny, ny};
        r.nz = (v2f){nz, nz}; r.w  = (v2f){w, w};
        dst[i] = r;
        keys[t] = ~0ULL;
    }
}

// Main: per ref j (uniform SGPR load), ONE asm volatile computes all 4 packed
// distances (28 VOP3P, 4-way interleaved). Volatile => cannot be duplicated
// => the j-loop cannot be fissioned into per-chain sweeps.
//   d.half = fl( fl(sr+sq) + fl(fl(fl(-2x*qx)+fl(-2y*qy))+fl(-2z*qz)) )
//          = fl( fl(xx+yy) - fl(2*zz) )   == numpy P bit-exactly.
// Strict < + ascending j == numpy first-occurrence argmin; cross-segment
// merge via u64 atomicMin of (ordmap(d)<<32 | idx). Deterministic.
__global__ __launch_bounds__(256, 4) void chamfer_main(
    const float* __restrict__ preds, const float* __restrict__ gts,
    const RefB* __restrict__ ppack, const RefB* __restrict__ gpack,
    unsigned long long* __restrict__ keys)
{
    int bid = blockIdx.x;
    int dir = bid / (NQB * NSEG);
    int rem = bid - dir * (NQB * NSEG);
    int seg = rem / NQB;
    int qb  = rem - seg * NQB;

    const float* qpts = (dir == 0) ? preds : gts;
    const RefB*  rb   = (dir == 0) ? gpack : ppack;

    int qbase = qb * QPB + threadIdx.x;

    // 4 chainpairs, each holding 2 queries in packed halves (lo=A, hi=B)
#define LOADQP(c)                                                         \
    v2f qx##c, qy##c, qz##c, sq##c;                                       \
    float bestA##c, bestB##c; int idxA##c, idxB##c;                       \
    {   int qA = qbase + (2*c) * 256, qB = qbase + (2*c+1) * 256;         \
        int cA = (qA < N_PTS) ? qA : (N_PTS - 1);                         \
        int cB = (qB < N_PTS) ? qB : (N_PTS - 1);                         \
        float xA = qpts[cA*3+0], yA = qpts[cA*3+1], zA = qpts[cA*3+2];    \
        float xB = qpts[cB*3+0], yB = qpts[cB*3+1], zB = qpts[cB*3+2];    \
        qx##c = (v2f){xA, xB}; qy##c = (v2f){yA, yB};                     \
        qz##c = (v2f){zA, zB};                                            \
        sq##c = (v2f){np_self_dot(xA, yA, zA), np_self_dot(xB, yB, zB)};  \
        bestA##c = 3.4e38f; bestB##c = 3.4e38f;                           \
        idxA##c = 0; idxB##c = 0; }
    LOADQP(0) LOADQP(1) LOADQP(2) LOADQP(3)
#undef LOADQP

    int s0 = seg * SEGLEN;
    int s1 = min(s0 + SEGLEN, N_PTS);

    #pragma unroll 2
    for (int j = s0; j < s1; ++j) {
        RefB r = rb[j];                  // wave-uniform -> s_load_dwordx8
        v2f d0, d1, d2, d3, t0, t1, t2, t3;
        asm volatile(
            // stage 1: d_c = (-2x)*qx_c
            "v_pk_mul_f32 %[d0], %[rx], %[qx0]\n\t"
            "v_pk_mul_f32 %[d1], %[rx], %[qx1]\n\t"
            "v_pk_mul_f32 %[d2], %[rx], %[qx2]\n\t"
            "v_pk_mul_f32 %[d3], %[rx], %[qx3]\n\t"
            // stage 2: t_c = (-2y)*qy_c
            "v_pk_mul_f32 %[t0], %[ry], %[qy0]\n\t"
            "v_pk_mul_f32 %[t1], %[ry], %[qy1]\n\t"
            "v_pk_mul_f32 %[t2], %[ry], %[qy2]\n\t"
            "v_pk_mul_f32 %[t3], %[ry], %[qy3]\n\t"
            // stage 3: d_c += t_c
            "v_pk_add_f32 %[d0], %[d0], %[t0]\n\t"
            "v_pk_add_f32 %[d1], %[d1], %[t1]\n\t"
            "v_pk_add_f32 %[d2], %[d2], %[t2]\n\t"
            "v_pk_add_f32 %[d3], %[d3], %[t3]\n\t"
            // stage 4: t_c = (-2z)*qz_c
            "v_pk_mul_f32 %[t0], %[rz], %[qz0]\n\t"
            "v_pk_mul_f32 %[t1], %[rz], %[qz1]\n\t"
            "v_pk_mul_f32 %[t2], %[rz], %[qz2]\n\t"
            "v_pk_mul_f32 %[t3], %[rz], %[qz3]\n\t"
            // stage 5: d_c += t_c   (d = -2*zz)
            "v_pk_add_f32 %[d0], %[d0], %[t0]\n\t"
            "v_pk_add_f32 %[d1], %[d1], %[t1]\n\t"
            "v_pk_add_f32 %[d2], %[d2], %[t2]\n\t"
            "v_pk_add_f32 %[d3], %[d3], %[t3]\n\t"
            // stage 6: t_c = sr + sq_c
            "v_pk_add_f32 %[t0], %[rw], %[sq0]\n\t"
            "v_pk_add_f32 %[t1], %[rw], %[sq1]\n\t"
            "v_pk_add_f32 %[t2], %[rw], %[sq2]\n\t"
            "v_pk_add_f32 %[t3], %[rw], %[sq3]\n\t"
            // stage 7: d_c = t_c + d_c   (d = (sq+sr) - 2zz)
            "v_pk_add_f32 %[d0], %[t0], %[d0]\n\t"
            "v_pk_add_f32 %[d1], %[t1], %[d1]\n\t"
            "v_pk_add_f32 %[d2], %[t2], %[d2]\n\t"
            "v_pk_add_f32 %[d3], %[t3], %[d3]"
            : [d0]"=&v"(d0), [d1]"=&v"(d1), [d2]"=&v"(d2), [d3]"=&v"(d3),
              [t0]"=&v"(t0), [t1]"=&v"(t1), [t2]"=&v"(t2), [t3]"=&v"(t3)
            : [rx]"s"(r.nx), [ry]"s"(r.ny), [rz]"s"(r.nz), [rw]"s"(r.w),
              [qx0]"v"(qx0), [qy0]"v"(qy0), [qz0]"v"(qz0), [sq0]"v"(sq0),
              [qx1]"v"(qx1), [qy1]"v"(qy1), [qz1]"v"(qz1), [sq1]"v"(sq1),
              [qx2]"v"(qx2), [qy2]"v"(qy2), [qz2]"v"(qz2), [sq2]"v"(sq2),
              [qx3]"v"(qx3), [qy3]"v"(qy3), [qz3]"v"(qz3), [sq3]"v"(sq3));

#define SEL(c)                                                            \
        { bool la = d##c.x < bestA##c;                                    \
          bestA##c = la ? d##c.x : bestA##c;                              \
          idxA##c  = la ? j      : idxA##c;                               \
          bool lb = d##c.y < bestB##c;                                    \
          bestB##c = lb ? d##c.y : bestB##c;                              \
          idxB##c  = lb ? j      : idxB##c; }
        SEL(0) SEL(1) SEL(2) SEL(3)
#undef SEL
    }

#define EMIT(c)                                                           \
    {   int qA = qbase + (2*c) * 256, qB = qbase + (2*c+1) * 256;         \
        if (qA < N_PTS) {                                                 \
            unsigned long long k =                                        \
                ((unsigned long long)ordmap(bestA##c) << 32) |            \
                (unsigned int)idxA##c;                                    \
            atomicMin(&keys[dir * N_PTS + qA], k);                        \
        }                                                                 \
        if (qB < N_PTS) {                                                 \
            unsigned long long k =                                        \
                ((unsigned long long)ordmap(bestB##c) << 32) |            \
                (unsigned int)idxB##c;                                    \
            atomicMin(&keys[dir * N_PTS + qB], k);                        \
        } }
    EMIT(0) EMIT(1) EMIT(2) EMIT(3)
#undef EMIT
}

__global__ __launch_bounds__(256) void chamfer_finalize(
    const unsigned long long* __restrict__ keys,
    float* __restrict__ out)
{
    int t = blockIdx.x * 256 + threadIdx.x;
    if (t >= 2 * N_PTS) return;
    int dir = t / N_PTS;
    int q   = t - dir * N_PTS;
    unsigned long long key = keys[dir * N_PTS + q];
    unsigned int hi = (unsigned int)(key >> 32);
    unsigned int lo = (unsigned int)(key & 0xFFFFFFFFu);
    unsigned int b  = (hi & 0x80000000u) ? (hi ^ 0x80000000u) : ~hi;
    out[dir * N_PTS + q]       = __uint_as_float(b);   // dist1 | dist2
    out[(2 + dir) * N_PTS + q] = (float)lo;            // idx1  | idx2
}

// ---- fallback (tiny workspace): direct kernel, correct but slow ----
__device__ __forceinline__ float np_pair(float sq, float sr,
                                         float qx, float qy, float qz,
                                         float rx, float ry, float rz) {
    float zz = __fadd_rn(__fadd_rn(__fmul_rn(qx, rx), __fmul_rn(qy, ry)),
                         __fmul_rn(qz, rz));
    return __fsub_rn(__fadd_rn(sq, sr), __fadd_rn(zz, zz));
}

__global__ __launch_bounds__(256) void chamfer_direct_kernel(
    const float* __restrict__ preds,
    const float* __restrict__ gts,
    float* __restrict__ out)
{
    __shared__ float4 spts[256];
    int bid = blockIdx.x;
    int dir = bid / QB79;
    int qb  = bid - dir * QB79;
    int q   = qb * 256 + threadIdx.x;

    const float* qpts = (dir == 0) ? preds : gts;
    const float* rpts = (dir == 0) ? gts   : preds;

    int qc = (q < N_PTS) ? q : (N_PTS - 1);
    float qx = qpts[qc*3+0], qy = qpts[qc*3+1], qz = qpts[qc*3+2];
    float sq = np_self_dot(qx, qy, qz);
    float best = 3.4e38f;
    int   bidx = 0;

    for (int t = 0; t < N_PTS; t += 256) {
        int cnt = min(256, N_PTS - t);
        __syncthreads();
        if ((int)threadIdx.x < cnt) {
            int j = t + threadIdx.x;
            float rx = rpts[j*3+0], ry = rpts[j*3+1], rz = rpts[j*3+2];
            spts[threadIdx.x] = make_float4(rx, ry, rz, np_self_dot(rx, ry, rz));
        }
        __syncthreads();
        for (int k = 0; k < cnt; ++k) {
            float4 r = spts[k];
            float d = np_pair(sq, r.w, qx, qy, qz, r.x, r.y, r.z);
            if (d < best) { best = d; bidx = t + k; }
        }
    }
    if (q < N_PTS) {
        out[dir * N_PTS + q]       = best;
        out[(2 + dir) * N_PTS + q] = (float)bidx;
    }
}

extern "C" void kernel_launch(void* const* d_in, const int* in_sizes, int n_in,
                              void* d_out, int out_size, void* d_ws, size_t ws_size,
                              hipStream_t stream) {
    const float* preds = (const float*)d_in[0];  // [20000, 3]
    const float* gts   = (const float*)d_in[1];  // [1, 20000, 3]
    float* out = (float*)d_out;

    size_t pack_bytes = (size_t)N_PTS * sizeof(RefB);                      // 640 KB each
    size_t keys_bytes = (size_t)2 * N_PTS * sizeof(unsigned long long);    // 320 KB
    size_t need = 2 * pack_bytes + keys_bytes;                             // ~1.6 MB

    if (ws_size >= need) {
        RefB* ppack = (RefB*)d_ws;
        RefB* gpack = (RefB*)((char*)d_ws + pack_bytes);
        unsigned long long* keys =
            (unsigned long long*)((char*)d_ws + 2 * pack_bytes);

        chamfer_prep<<<(2 * N_PTS + 255) / 256, 256, 0, stream>>>(
            preds, gts, ppack, gpack, keys);
        chamfer_main<<<2 * NQB * NSEG, 256, 0, stream>>>(
            preds, gts, ppack, gpack, keys);              // 1280 blocks
        chamfer_finalize<<<(2 * N_PTS + 255) / 256, 256, 0, stream>>>(keys, out);
    } else {
        chamfer_direct_kernel<<<2 * QB79, 256, 0, stream>>>(preds, gts, out);
    }
}

// Round 9
// 192.493 us; speedup vs baseline: 1.2685x; 1.2609x over previous
//
#include <hip/hip_runtime.h>

#define N_PTS  20000
#define NB     1024                 // x-buckets per cloud
#define XMINF  (-6.0f)              // gaussian range with huge slack
#define INVW   (NB / 12.0f)
#define MARGIN 1e-3f                // >> 2e-5 worst-case |P_np - d_true^2|
#define QB79   79                   // fallback

// ---- numpy-exact helpers (proven in rounds 2/5) ----
__device__ __forceinline__ float np_self_dot(float x, float y, float z) {
    return __fadd_rn(__fadd_rn(__fmul_rn(x, x), __fmul_rn(y, y)),
                     __fmul_rn(z, z));
}
__device__ __forceinline__ unsigned ordmap(float f) {
    unsigned b = __float_as_uint(f);
    return (b & 0x80000000u) ? ~b : (b | 0x80000000u);
}
__device__ __forceinline__ float invord(unsigned h) {
    return __uint_as_float((h & 0x80000000u) ? (h ^ 0x80000000u) : ~h);
}
__device__ __forceinline__ int bucketOf(float x) {
    int b = (int)((x - XMINF) * INVW);       // truncation==floor for b>=0
    return b < 0 ? 0 : (b > NB - 1 ? NB - 1 : b);
}
__device__ __forceinline__ unsigned long long wave_min_u64(unsigned long long k) {
    #pragma unroll
    for (int m = 1; m < 64; m <<= 1) {
        unsigned long long o = __shfl_xor(k, m, 64);
        k = (o < k) ? o : k;
    }
    return k;
}

// ---- build: histogram -> prefix-scan -> scatter (bucket sort by x) ----
__global__ __launch_bounds__(256) void k_hist(
    const float* __restrict__ preds, const float* __restrict__ gts,
    int* __restrict__ counts)
{
    int t = blockIdx.x * 256 + threadIdx.x;
    if (t >= 2 * N_PTS) return;
    int cl = t / N_PTS, i = t - cl * N_PTS;
    const float* src = cl ? gts : preds;
    atomicAdd(&counts[cl * NB + bucketOf(src[i * 3])], 1);
}

__global__ __launch_bounds__(NB) void k_scan(
    const int* __restrict__ counts, int* __restrict__ bstart,
    int* __restrict__ cursor)
{
    __shared__ int buf[NB];
    int c = blockIdx.x, t = threadIdx.x;
    int v = counts[c * NB + t];
    buf[t] = v;
    __syncthreads();
    for (int off = 1; off < NB; off <<= 1) {
        int add = (t >= off) ? buf[t - off] : 0;
        __syncthreads();
        buf[t] += add;
        __syncthreads();
    }
    int incl = buf[t], excl = incl - v;
    bstart[c * (NB + 1) + t] = excl;
    cursor[c * NB + t] = excl;
    if (t == NB - 1) bstart[c * (NB + 1) + NB] = incl;   // == N_PTS
}

__global__ __launch_bounds__(256) void k_scatter(
    const float* __restrict__ preds, const float* __restrict__ gts,
    int* __restrict__ cursor, float4* __restrict__ sorted,
    int* __restrict__ sidx)
{
    int t = blockIdx.x * 256 + threadIdx.x;
    if (t >= 2 * N_PTS) return;
    int cl = t / N_PTS, i = t - cl * N_PTS;
    const float* src = cl ? gts : preds;
    float x = src[i*3+0], y = src[i*3+1], z = src[i*3+2];
    int pos = atomicAdd(&cursor[cl * NB + bucketOf(x)], 1);
    sorted[cl * N_PTS + pos] = make_float4(x, y, z, np_self_dot(x, y, z));
    sidx[cl * N_PTS + pos] = i;
}

// ---- main: one wave per query; seed 64 -> prune window -> exact scan ----
// P computed with r2/r5's proven numpy-exact rounding. Window safety:
// argmin ref r* has dx^2 <= d_true^2(r*) <= P_np(r*) + 2e-5 <= best0 + MARGIN.
// Key = (ordmap(P)<<32 | orig_idx): wave-min == (min P, then min orig idx)
// == numpy first-occurrence argmin; order-independent -> deterministic.
__global__ __launch_bounds__(256) void k_main(
    const float4* __restrict__ sorted, const int* __restrict__ sidx,
    const int* __restrict__ bstart, float* __restrict__ out)
{
    int wid  = blockIdx.x * 4 + ((int)threadIdx.x >> 6);   // 0..39999
    int lane = threadIdx.x & 63;
    int dir  = wid / N_PTS;
    int qpos = wid - dir * N_PTS;
    int rcl  = 1 - dir;

    const float4* qs = sorted + (size_t)dir * N_PTS;
    const float4* rs = sorted + (size_t)rcl * N_PTS;
    const int*    ri = sidx   + (size_t)rcl * N_PTS;
    const int*    rb = bstart + rcl * (NB + 1);

    float4 qv   = qs[qpos];                 // wave-broadcast load
    int    origq = sidx[(size_t)dir * N_PTS + qpos];
    float qx = qv.x, qy = qv.y, qz = qv.z, sq = qv.w;

    // seed: 64 refs around the query's x-position
    int s = rb[bucketOf(qx)] - 32;
    s = s < 0 ? 0 : (s > N_PTS - 64 ? N_PTS - 64 : s);
    unsigned long long key;
    {
        int p = s + lane;
        float4 r = rs[p];
        float zz = __fadd_rn(__fadd_rn(__fmul_rn(qx, r.x), __fmul_rn(qy, r.y)),
                             __fmul_rn(qz, r.z));
        float P  = __fsub_rn(__fadd_rn(sq, r.w), __fadd_rn(zz, zz));
        key = ((unsigned long long)ordmap(P) << 32) | (unsigned)ri[p];
    }
    key = wave_min_u64(key);

    // prune window from the seed upper bound
    float W = sqrtf(invord((unsigned)(key >> 32)) + MARGIN);
    int lo_b = bucketOf(qx - W);
    int hi_b = bucketOf(qx + W);
    int rlo = rb[lo_b];
    int rhi = rb[hi_b + 1];

    for (int p = rlo + lane; p < rhi; p += 64) {
        float4 r = rs[p];
        float zz = __fadd_rn(__fadd_rn(__fmul_rn(qx, r.x), __fmul_rn(qy, r.y)),
                             __fmul_rn(qz, r.z));
        float P  = __fsub_rn(__fadd_rn(sq, r.w), __fadd_rn(zz, zz));
        unsigned long long k =
            ((unsigned long long)ordmap(P) << 32) | (unsigned)ri[p];
        key = (k < key) ? k : key;
    }
    key = wave_min_u64(key);

    if (lane == 0) {
        out[dir * N_PTS + origq]       = invord((unsigned)(key >> 32));
        out[(2 + dir) * N_PTS + origq] = (float)(unsigned)(key & 0xFFFFFFFFu);
    }
}

// ---- fallback (tiny workspace): brute-force direct kernel ----
__device__ __forceinline__ float np_pair(float sq, float sr,
                                         float qx, float qy, float qz,
                                         float rx, float ry, float rz) {
    float zz = __fadd_rn(__fadd_rn(__fmul_rn(qx, rx), __fmul_rn(qy, ry)),
                         __fmul_rn(qz, rz));
    return __fsub_rn(__fadd_rn(sq, sr), __fadd_rn(zz, zz));
}

__global__ __launch_bounds__(256) void chamfer_direct_kernel(
    const float* __restrict__ preds, const float* __restrict__ gts,
    float* __restrict__ out)
{
    __shared__ float4 spts[256];
    int bid = blockIdx.x;
    int dir = bid / QB79;
    int qb  = bid - dir * QB79;
    int q   = qb * 256 + threadIdx.x;

    const float* qpts = (dir == 0) ? preds : gts;
    const float* rpts = (dir == 0) ? gts   : preds;

    int qc = (q < N_PTS) ? q : (N_PTS - 1);
    float qx = qpts[qc*3+0], qy = qpts[qc*3+1], qz = qpts[qc*3+2];
    float sq = np_self_dot(qx, qy, qz);
    float best = 3.4e38f;
    int   bidx = 0;

    for (int t = 0; t < N_PTS; t += 256) {
        int cnt = min(256, N_PTS - t);
        __syncthreads();
        if ((int)threadIdx.x < cnt) {
            int j = t + threadIdx.x;
            float rx = rpts[j*3+0], ry = rpts[j*3+1], rz = rpts[j*3+2];
            spts[threadIdx.x] = make_float4(rx, ry, rz, np_self_dot(rx, ry, rz));
        }
        __syncthreads();
        for (int k = 0; k < cnt; ++k) {
            float4 r = spts[k];
            float d = np_pair(sq, r.w, qx, qy, qz, r.x, r.y, r.z);
            if (d < best) { best = d; bidx = t + k; }
        }
    }
    if (q < N_PTS) {
        out[dir * N_PTS + q]       = best;
        out[(2 + dir) * N_PTS + q] = (float)bidx;
    }
}

extern "C" void kernel_launch(void* const* d_in, const int* in_sizes, int n_in,
                              void* d_out, int out_size, void* d_ws, size_t ws_size,
                              hipStream_t stream) {
    const float* preds = (const float*)d_in[0];  // [20000, 3]
    const float* gts   = (const float*)d_in[1];  // [1, 20000, 3]
    float* out = (float*)d_out;

    char* w = (char*)d_ws;
    size_t sorted_b = (size_t)2 * N_PTS * sizeof(float4);   // 640000
    size_t sidx_b   = (size_t)2 * N_PTS * sizeof(int);      // 160000
    size_t counts_b = (size_t)2 * NB * sizeof(int);         //   8192
    size_t cursor_b = (size_t)2 * NB * sizeof(int);         //   8192
    size_t bstart_b = (size_t)2 * (NB + 1) * sizeof(int);   //   8200
    size_t need = sorted_b + sidx_b + counts_b + cursor_b + bstart_b;

    if (ws_size >= need) {
        float4* sorted = (float4*)w;
        int* sidx   = (int*)(w + sorted_b);
        int* counts = (int*)(w + sorted_b + sidx_b);
        int* cursor = (int*)(w + sorted_b + sidx_b + counts_b);
        int* bstart = (int*)(w + sorted_b + sidx_b + counts_b + cursor_b);

        hipMemsetAsync(counts, 0, counts_b, stream);
        int g = (2 * N_PTS + 255) / 256;                    // 157
        k_hist<<<g, 256, 0, stream>>>(preds, gts, counts);
        k_scan<<<2, NB, 0, stream>>>(counts, bstart, cursor);
        k_scatter<<<g, 256, 0, stream>>>(preds, gts, cursor, sorted, sidx);
        k_main<<<2 * N_PTS / 4, 256, 0, stream>>>(sorted, sidx, bstart, out);
    } else {
        chamfer_direct_kernel<<<2 * QB79, 256, 0, stream>>>(preds, gts, out);
    }
}

// Round 10
// 174.233 us; speedup vs baseline: 1.4014x; 1.1048x over previous
//
#include <hip/hip_runtime.h>

#define N_PTS  20000
#define NB     1024                 // x-buckets per cloud (== build block size)
#define XMINF  (-6.0f)
#define BW     (12.0f / NB)         // bucket width
#define INVW   (NB / 12.0f)
#define MARGIN 5e-4f                // >> 4e-5 worst-case |P_np - d_true^2|
#define QB79   79                   // fallback

// ---- numpy-exact helpers (proven rounds 2/5/9) ----
__device__ __forceinline__ float np_self_dot(float x, float y, float z) {
    return __fadd_rn(__fadd_rn(__fmul_rn(x, x), __fmul_rn(y, y)),
                     __fmul_rn(z, z));
}
__device__ __forceinline__ unsigned ordmap(float f) {
    unsigned b = __float_as_uint(f);
    return (b & 0x80000000u) ? ~b : (b | 0x80000000u);
}
__device__ __forceinline__ float invord(unsigned h) {
    return __uint_as_float((h & 0x80000000u) ? (h ^ 0x80000000u) : ~h);
}
__device__ __forceinline__ int bucketOf(float x) {
    int b = (int)((x - XMINF) * INVW);
    return b < 0 ? 0 : (b > NB - 1 ? NB - 1 : b);
}
__device__ __forceinline__ unsigned long long wave_min_u64(unsigned long long k) {
    #pragma unroll
    for (int m = 1; m < 64; m <<= 1) {
        unsigned long long o = __shfl_xor(k, m, 64);
        k = (o < k) ? o : k;
    }
    return k;
}

// ---- fused build: per-cloud LDS hist -> LDS scan -> scatter (1 block/cloud)
__global__ __launch_bounds__(NB) void k_build(
    const float* __restrict__ preds, const float* __restrict__ gts,
    float4* __restrict__ sorted, int* __restrict__ sidx,
    int* __restrict__ bstart)
{
    __shared__ int cnt[NB];
    __shared__ int cur[NB];
    int cl = blockIdx.x;                    // 0 = preds, 1 = gts
    int t  = threadIdx.x;
    const float* src = cl ? gts : preds;

    cnt[t] = 0;
    __syncthreads();
    for (int i = t; i < N_PTS; i += NB)
        atomicAdd(&cnt[bucketOf(src[i * 3])], 1);
    __syncthreads();

    int v = cnt[t];
    for (int off = 1; off < NB; off <<= 1) {       // Hillis-Steele inclusive
        int add = (t >= off) ? cnt[t - off] : 0;
        __syncthreads();
        cnt[t] += add;
        __syncthreads();
    }
    int incl = cnt[t], excl = incl - v;
    cur[t] = excl;
    bstart[cl * (NB + 1) + t] = excl;
    if (t == NB - 1) bstart[cl * (NB + 1) + NB] = incl;   // == N_PTS
    __syncthreads();

    for (int i = t; i < N_PTS; i += NB) {
        float x = src[i*3+0], y = src[i*3+1], z = src[i*3+2];
        int pos = atomicAdd(&cur[bucketOf(x)], 1);
        sorted[(size_t)cl * N_PTS + pos] = make_float4(x, y, z, np_self_dot(x, y, z));
        sidx[(size_t)cl * N_PTS + pos] = i;
    }
}

// ---- main: one wave/query; iteratively tightening bucket window ----
// Eval identical to r9 (bit-exact numpy P; key=(ordmap(P)<<32|orig_idx);
// wave-min == first-occurrence numpy argmin). Pruned refs satisfy
// dx^2 > best+MARGIN => P_np > best strictly (MARGIN >> rounding) — safe.
__global__ __launch_bounds__(256) void k_main(
    const float4* __restrict__ sorted, const int* __restrict__ sidx,
    const int* __restrict__ bstart, float* __restrict__ out)
{
    int wid  = blockIdx.x * 4 + ((int)threadIdx.x >> 6);   // 0..39999
    int lane = threadIdx.x & 63;
    int dir  = wid / N_PTS;
    int qpos = wid - dir * N_PTS;
    int rcl  = 1 - dir;

    const float4* rs = sorted + (size_t)rcl * N_PTS;
    const int*    ri = sidx   + (size_t)rcl * N_PTS;
    const int*    rb = bstart + rcl * (NB + 1);

    float4 qv    = sorted[(size_t)dir * N_PTS + qpos];     // wave-broadcast
    int    origq = sidx[(size_t)dir * N_PTS + qpos];
    float qx = qv.x, qy = qv.y, qz = qv.z, sq = qv.w;

    unsigned long long key = ~0ULL;

#define EVAL(p)                                                            \
    {   float4 r = rs[p];                                                  \
        float zz = __fadd_rn(__fadd_rn(__fmul_rn(qx, r.x),                 \
                                       __fmul_rn(qy, r.y)),                \
                             __fmul_rn(qz, r.z));                          \
        float P  = __fsub_rn(__fadd_rn(sq, r.w), __fadd_rn(zz, zz));       \
        unsigned long long k =                                             \
            ((unsigned long long)ordmap(P) << 32) | (unsigned)ri[p];       \
        key = (k < key) ? k : key; }

    // seed: query's bucket +-2
    int b0 = bucketOf(qx);
    int sL = b0 - 2 < 0 ? 0 : b0 - 2;
    int sR = b0 + 2 > NB - 1 ? NB - 1 : b0 + 2;
    for (int p = rb[sL] + lane; p < rb[sR + 1]; p += 64) EVAL(p)

    // tighten: recompute window from wave-best, scan only new buckets
    for (int round = 0; round < 40; ++round) {
        key = wave_min_u64(key);
        float best = invord((unsigned)(key >> 32));
        int tL, tR;
        if (best < 1e30f) {
            float W = sqrtf(best + MARGIN);
            tL = bucketOf(qx - W);
            tR = bucketOf(qx + W);
        } else {                                   // nothing found yet (tails)
            int grow = sR - sL + 1;
            tL = sL - grow; tR = sR + grow;
            tL = tL < 0 ? 0 : tL;
            tR = tR > NB - 1 ? NB - 1 : tR;
        }
        if (tL >= sL && tR <= sR) break;           // window inside scanned
        if (tL < sL) {
            for (int p = rb[tL] + lane; p < rb[sL]; p += 64) EVAL(p)
            sL = tL;
        }
        if (tR > sR) {
            for (int p = rb[sR + 1] + lane; p < rb[tR + 1]; p += 64) EVAL(p)
            sR = tR;
        }
    }
#undef EVAL

    key = wave_min_u64(key);
    if (lane == 0) {
        out[dir * N_PTS + origq]       = invord((unsigned)(key >> 32));
        out[(2 + dir) * N_PTS + origq] = (float)(unsigned)(key & 0xFFFFFFFFu);
    }
}

// ---- fallback (tiny workspace): brute-force direct kernel (proven r2) ----
__device__ __forceinline__ float np_pair(float sq, float sr,
                                         float qx, float qy, float qz,
                                         float rx, float ry, float rz) {
    float zz = __fadd_rn(__fadd_rn(__fmul_rn(qx, rx), __fmul_rn(qy, ry)),
                         __fmul_rn(qz, rz));
    return __fsub_rn(__fadd_rn(sq, sr), __fadd_rn(zz, zz));
}

__global__ __launch_bounds__(256) void chamfer_direct_kernel(
    const float* __restrict__ preds, const float* __restrict__ gts,
    float* __restrict__ out)
{
    __shared__ float4 spts[256];
    int bid = blockIdx.x;
    int dir = bid / QB79;
    int qb  = bid - dir * QB79;
    int q   = qb * 256 + threadIdx.x;

    const float* qpts = (dir == 0) ? preds : gts;
    const float* rpts = (dir == 0) ? gts   : preds;

    int qc = (q < N_PTS) ? q : (N_PTS - 1);
    float qx = qpts[qc*3+0], qy = qpts[qc*3+1], qz = qpts[qc*3+2];
    float sq = np_self_dot(qx, qy, qz);
    float best = 3.4e38f;
    int   bidx = 0;

    for (int t = 0; t < N_PTS; t += 256) {
        int cnt = min(256, N_PTS - t);
        __syncthreads();
        if ((int)threadIdx.x < cnt) {
            int j = t + threadIdx.x;
            float rx = rpts[j*3+0], ry = rpts[j*3+1], rz = rpts[j*3+2];
            spts[threadIdx.x] = make_float4(rx, ry, rz, np_self_dot(rx, ry, rz));
        }
        __syncthreads();
        for (int k = 0; k < cnt; ++k) {
            float4 r = spts[k];
            float d = np_pair(sq, r.w, qx, qy, qz, r.x, r.y, r.z);
            if (d < best) { best = d; bidx = t + k; }
        }
    }
    if (q < N_PTS) {
        out[dir * N_PTS + q]       = best;
        out[(2 + dir) * N_PTS + q] = (float)bidx;
    }
}

extern "C" void kernel_launch(void* const* d_in, const int* in_sizes, int n_in,
                              void* d_out, int out_size, void* d_ws, size_t ws_size,
                              hipStream_t stream) {
    const float* preds = (const float*)d_in[0];  // [20000, 3]
    const float* gts   = (const float*)d_in[1];  // [1, 20000, 3]
    float* out = (float*)d_out;

    char* w = (char*)d_ws;
    size_t sorted_b = (size_t)2 * N_PTS * sizeof(float4);   // 640000
    size_t sidx_b   = (size_t)2 * N_PTS * sizeof(int);      // 160000
    size_t bstart_b = (size_t)2 * (NB + 1) * sizeof(int);   //   8200
    size_t need = sorted_b + sidx_b + bstart_b;

    if (ws_size >= need) {
        float4* sorted = (float4*)w;
        int* sidx   = (int*)(w + sorted_b);
        int* bstart = (int*)(w + sorted_b + sidx_b);

        k_build<<<2, NB, 0, stream>>>(preds, gts, sorted, sidx, bstart);
        k_main<<<2 * N_PTS / 4, 256, 0, stream>>>(sorted, sidx, bstart, out);
    } else {
        chamfer_direct_kernel<<<2 * QB79, 256, 0, stream>>>(preds, gts, out);
    }
}

// Round 11
// 153.473 us; speedup vs baseline: 1.5910x; 1.1353x over previous
//
#include <hip/hip_runtime.h>

#define N_PTS  20000
#define NG     128                  // grid is NG x NG over [-6,6]^2
#define NC     (NG * NG)            // 16384 cells per cloud
#define GMIN   (-6.0f)
#define GINV   (NG / 12.0f)
#define MARGIN 5e-4f                // >> 2e-5 worst-case |P_np - d_true^2|
#define QB79   79                   // fallback

// ---- numpy-exact helpers (proven rounds 2/5/9/10) ----
__device__ __forceinline__ float np_self_dot(float x, float y, float z) {
    return __fadd_rn(__fadd_rn(__fmul_rn(x, x), __fmul_rn(y, y)),
                     __fmul_rn(z, z));
}
__device__ __forceinline__ unsigned ordmap(float f) {
    unsigned b = __float_as_uint(f);
    return (b & 0x80000000u) ? ~b : (b | 0x80000000u);
}
__device__ __forceinline__ float invord(unsigned h) {
    return __uint_as_float((h & 0x80000000u) ? (h ^ 0x80000000u) : ~h);
}
__device__ __forceinline__ int cellC(float v) {
    int c = (int)((v - GMIN) * GINV);
    return c < 0 ? 0 : (c > NG - 1 ? NG - 1 : c);
}
__device__ __forceinline__ unsigned long long wave_min_u64(unsigned long long k) {
    #pragma unroll
    for (int m = 1; m < 64; m <<= 1) {
        unsigned long long o = __shfl_xor(k, m, 64);
        k = (o < k) ? o : k;
    }
    return k;
}

// ---- build stage 1: global-atomic histogram (157 blocks) ----
__global__ __launch_bounds__(256) void k_hist(
    const float* __restrict__ preds, const float* __restrict__ gts,
    int* __restrict__ counts)
{
    int t = blockIdx.x * 256 + threadIdx.x;
    if (t >= 2 * N_PTS) return;
    int cl = t / N_PTS, i = t - cl * N_PTS;
    const float* src = cl ? gts : preds;
    int cell = cellC(src[i*3+0]) * NG + cellC(src[i*3+1]);
    atomicAdd(&counts[cl * NC + cell], 1);
}

// ---- build stage 2: chunked scan, 1 block/cloud, 16 cells/thread ----
__global__ __launch_bounds__(1024) void k_scan(
    const int* __restrict__ counts, int* __restrict__ bstart,
    int* __restrict__ cursor)
{
    __shared__ int part[1024];
    int cl = blockIdx.x, t = threadIdx.x;
    const int* c = counts + cl * NC;
    int base = t * 16;
    int v[16], s = 0;
    #pragma unroll
    for (int i = 0; i < 16; ++i) { v[i] = c[base + i]; s += v[i]; }
    part[t] = s;
    __syncthreads();
    for (int off = 1; off < 1024; off <<= 1) {     // Hillis-Steele inclusive
        int add = (t >= off) ? part[t - off] : 0;
        __syncthreads();
        part[t] += add;
        __syncthreads();
    }
    int run = part[t] - s;                          // exclusive prefix
    #pragma unroll
    for (int i = 0; i < 16; ++i) {
        bstart[cl * (NC + 1) + base + i] = run;
        cursor[cl * NC + base + i] = run;
        run += v[i];
    }
    if (t == 1023) bstart[cl * (NC + 1) + NC] = run;   // == N_PTS
}

// ---- build stage 3: scatter into cell-sorted order (157 blocks) ----
__global__ __launch_bounds__(256) void k_scatter(
    const float* __restrict__ preds, const float* __restrict__ gts,
    int* __restrict__ cursor, float4* __restrict__ sorted,
    int* __restrict__ sidx)
{
    int t = blockIdx.x * 256 + threadIdx.x;
    if (t >= 2 * N_PTS) return;
    int cl = t / N_PTS, i = t - cl * N_PTS;
    const float* src = cl ? gts : preds;
    float x = src[i*3+0], y = src[i*3+1], z = src[i*3+2];
    int cell = cellC(x) * NG + cellC(y);
    int pos = atomicAdd(&cursor[cl * NC + cell], 1);
    sorted[(size_t)cl * N_PTS + pos] = make_float4(x, y, z, np_self_dot(x, y, z));
    sidx[(size_t)cl * N_PTS + pos] = i;
}

// ---- main: one wave/query; 2D cell window, seed 3x3 -> tighten ----
// Eval bit-identical to r9/r10 (numpy-exact P; key=(ordmap(P)<<32|orig_idx);
// wave-min == numpy first-occurrence argmin). Pruned p: |dx|>W or |dy|>W
// => d^2 > best+MARGIN => P_np > best strictly. Rescans idempotent.
__global__ __launch_bounds__(256) void k_main(
    const float4* __restrict__ sorted, const int* __restrict__ sidx,
    const int* __restrict__ bstart, float* __restrict__ out)
{
    int wid  = blockIdx.x * 4 + ((int)threadIdx.x >> 6);   // 0..39999
    int lane = threadIdx.x & 63;
    int dir  = wid / N_PTS;
    int qpos = wid - dir * N_PTS;
    int rcl  = 1 - dir;

    const float4* rs = sorted + (size_t)rcl * N_PTS;
    const int*    ri = sidx   + (size_t)rcl * N_PTS;
    const int*    cs = bstart + rcl * (NC + 1);

    float4 qv    = sorted[(size_t)dir * N_PTS + qpos];     // wave-broadcast
    int    origq = sidx[(size_t)dir * N_PTS + qpos];
    float qx = qv.x, qy = qv.y, qz = qv.z, sq = qv.w;

    unsigned long long key = ~0ULL;

#define EVAL(p)                                                            \
    {   float4 r = rs[p];                                                  \
        float zz = __fadd_rn(__fadd_rn(__fmul_rn(qx, r.x),                 \
                                       __fmul_rn(qy, r.y)),                \
                             __fmul_rn(qz, r.z));                          \
        float P  = __fsub_rn(__fadd_rn(sq, r.w), __fadd_rn(zz, zz));       \
        unsigned long long kk =                                            \
            ((unsigned long long)ordmap(P) << 32) | (unsigned)ri[p];       \
        key = (kk < key) ? kk : key; }

#define ROW(x, ya, yb)                                                     \
    if ((yb) >= (ya)) {                                                    \
        int lo = cs[(x) * NG + (ya)], hi = cs[(x) * NG + (yb) + 1];        \
        for (int p = lo + lane; p < hi; p += 64) EVAL(p)                   \
    }

    int cx = cellC(qx), cy = cellC(qy);
    int sxL = cx > 0 ? cx - 1 : 0,      sxR = cx < NG-1 ? cx + 1 : NG-1;
    int syL = cy > 0 ? cy - 1 : 0,      syR = cy < NG-1 ? cy + 1 : NG-1;

    for (int x = sxL; x <= sxR; ++x) ROW(x, syL, syR)      // seed 3x3

    for (int round = 0; round < 24; ++round) {
        key = wave_min_u64(key);
        int txL, txR, tyL, tyR;
        if (key != ~0ULL) {
            float W = sqrtf(invord((unsigned)(key >> 32)) + MARGIN);
            txL = cellC(qx - W); txR = cellC(qx + W);
            tyL = cellC(qy - W); tyR = cellC(qy + W);
        } else {                                           // empty seed: grow
            int gx = sxR - sxL + 1, gy = syR - syL + 1;
            txL = sxL - gx; txR = sxR + gx;
            tyL = syL - gy; tyR = syR + gy;
            txL = txL < 0 ? 0 : txL;  tyL = tyL < 0 ? 0 : tyL;
            txR = txR > NG-1 ? NG-1 : txR;
            tyR = tyR > NG-1 ? NG-1 : tyR;
        }
        if (txL >= sxL && txR <= sxR && tyL >= syL && tyR <= syR) break;
        for (int x = txL; x <= txR; ++x) {
            if (x >= sxL && x <= sxR) {                    // only new strips
                ROW(x, tyL, syL - 1)
                ROW(x, syR + 1, tyR)
            } else {
                ROW(x, tyL, tyR)
            }
        }
        sxL = txL; sxR = txR; syL = tyL; syR = tyR;
    }
#undef ROW
#undef EVAL

    key = wave_min_u64(key);
    if (lane == 0) {
        out[dir * N_PTS + origq]       = invord((unsigned)(key >> 32));
        out[(2 + dir) * N_PTS + origq] = (float)(unsigned)(key & 0xFFFFFFFFu);
    }
}

// ---- fallback (tiny workspace): brute-force direct kernel (proven r2) ----
__device__ __forceinline__ float np_pair(float sq, float sr,
                                         float qx, float qy, float qz,
                                         float rx, float ry, float rz) {
    float zz = __fadd_rn(__fadd_rn(__fmul_rn(qx, rx), __fmul_rn(qy, ry)),
                         __fmul_rn(qz, rz));
    return __fsub_rn(__fadd_rn(sq, sr), __fadd_rn(zz, zz));
}

__global__ __launch_bounds__(256) void chamfer_direct_kernel(
    const float* __restrict__ preds, const float* __restrict__ gts,
    float* __restrict__ out)
{
    __shared__ float4 spts[256];
    int bid = blockIdx.x;
    int dir = bid / QB79;
    int qb  = bid - dir * QB79;
    int q   = qb * 256 + threadIdx.x;

    const float* qpts = (dir == 0) ? preds : gts;
    const float* rpts = (dir == 0) ? gts   : preds;

    int qc = (q < N_PTS) ? q : (N_PTS - 1);
    float qx = qpts[qc*3+0], qy = qpts[qc*3+1], qz = qpts[qc*3+2];
    float sq = np_self_dot(qx, qy, qz);
    float best = 3.4e38f;
    int   bidx = 0;

    for (int t = 0; t < N_PTS; t += 256) {
        int cnt = min(256, N_PTS - t);
        __syncthreads();
        if ((int)threadIdx.x < cnt) {
            int j = t + threadIdx.x;
            float rx = rpts[j*3+0], ry = rpts[j*3+1], rz = rpts[j*3+2];
            spts[threadIdx.x] = make_float4(rx, ry, rz, np_self_dot(rx, ry, rz));
        }
        __syncthreads();
        for (int k = 0; k < cnt; ++k) {
            float4 r = spts[k];
            float d = np_pair(sq, r.w, qx, qy, qz, r.x, r.y, r.z);
            if (d < best) { best = d; bidx = t + k; }
        }
    }
    if (q < N_PTS) {
        out[dir * N_PTS + q]       = best;
        out[(2 + dir) * N_PTS + q] = (float)bidx;
    }
}

extern "C" void kernel_launch(void* const* d_in, const int* in_sizes, int n_in,
                              void* d_out, int out_size, void* d_ws, size_t ws_size,
                              hipStream_t stream) {
    const float* preds = (const float*)d_in[0];  // [20000, 3]
    const float* gts   = (const float*)d_in[1];  // [1, 20000, 3]
    float* out = (float*)d_out;

    char* w = (char*)d_ws;
    size_t sorted_b = (size_t)2 * N_PTS * sizeof(float4);   // 640000
    size_t sidx_b   = (size_t)2 * N_PTS * sizeof(int);      // 160000
    size_t counts_b = (size_t)2 * NC * sizeof(int);         // 131072
    size_t cursor_b = (size_t)2 * NC * sizeof(int);         // 131072
    size_t bstart_b = (size_t)2 * (NC + 1) * sizeof(int);   // 131080
    size_t need = sorted_b + sidx_b + counts_b + cursor_b + bstart_b;

    if (ws_size >= need) {
        float4* sorted = (float4*)w;
        int* sidx   = (int*)(w + sorted_b);
        int* counts = (int*)(w + sorted_b + sidx_b);
        int* cursor = (int*)(w + sorted_b + sidx_b + counts_b);
        int* bstart = (int*)(w + sorted_b + sidx_b + counts_b + cursor_b);

        hipMemsetAsync(counts, 0, counts_b, stream);
        int g = (2 * N_PTS + 255) / 256;                    // 157
        k_hist<<<g, 256, 0, stream>>>(preds, gts, counts);
        k_scan<<<2, 1024, 0, stream>>>(counts, bstart, cursor);
        k_scatter<<<g, 256, 0, stream>>>(preds, gts, cursor, sorted, sidx);
        k_main<<<2 * N_PTS / 4, 256, 0, stream>>>(sorted, sidx, bstart, out);
    } else {
        chamfer_direct_kernel<<<2 * QB79, 256, 0, stream>>>(preds, gts, out);
    }
}